// Round 3
// baseline (685.828 us; speedup 1.0000x reference)
//
#include <hip/hip_runtime.h>

#define N_NODES 50000
#define N_EDGES 800000
#define IN_DIM  256
#define H1      512
#define H2      128

// ---------------- CSR build kernels ----------------

__global__ void init_kernel(float* deg, int* cnt, int n) {
    int i = blockIdx.x * blockDim.x + threadIdx.x;
    if (i < n) { deg[i] = 1.0f; cnt[i] = 0; }   // deg starts at 1.0 (self-loop weight)
}

__global__ void edge_deg_kernel(const int* __restrict__ col, const float* __restrict__ ew,
                                float* deg, int* cnt, int ne) {
    int e = blockIdx.x * blockDim.x + threadIdx.x;
    if (e < ne) {
        int c = col[e];
        atomicAdd(&deg[c], ew[e]);
        atomicAdd(&cnt[c], 1);
    }
}

__global__ void dinv_kernel(const float* __restrict__ deg, float* dinv, int n) {
    int i = blockIdx.x * blockDim.x + threadIdx.x;
    if (i < n) dinv[i] = rsqrtf(deg[i]);  // deg >= 1 always (self-loop)
}

// hierarchical exclusive scan: per-block scan -> top scan -> add offsets
__global__ void scan_block_kernel(const int* __restrict__ cnt, int* __restrict__ part,
                                  int* __restrict__ bsum, int n) {
    __shared__ int s[256];
    int tid = threadIdx.x;
    int i = blockIdx.x * 256 + tid;
    int v = (i < n) ? cnt[i] : 0;
    s[tid] = v; __syncthreads();
#pragma unroll
    for (int d = 1; d < 256; d <<= 1) {
        int t = (tid >= d) ? s[tid - d] : 0; __syncthreads();
        s[tid] += t; __syncthreads();
    }
    if (i < n) part[i] = s[tid] - v;           // exclusive within block
    if (tid == 255) bsum[blockIdx.x] = s[255]; // block total
}

__global__ void scan_tops_kernel(const int* __restrict__ bsum, int* __restrict__ boff, int nb) {
    __shared__ int s[256];
    int tid = threadIdx.x;
    int v = (tid < nb) ? bsum[tid] : 0;
    s[tid] = v; __syncthreads();
#pragma unroll
    for (int d = 1; d < 256; d <<= 1) {
        int t = (tid >= d) ? s[tid - d] : 0; __syncthreads();
        s[tid] += t; __syncthreads();
    }
    if (tid < nb) boff[tid] = s[tid] - v;      // exclusive across blocks
}

__global__ void scan_add_kernel(const int* __restrict__ part, const int* __restrict__ boff,
                                int* __restrict__ ptr, int* __restrict__ fill, int n) {
    int i = blockIdx.x * 256 + threadIdx.x;
    if (i < n) {
        int p = part[i] + boff[blockIdx.x];
        ptr[i] = p; fill[i] = p;
    }
    if (i == 0) ptr[n] = N_EDGES;              // total edges known at compile time
}

__global__ void scatter_kernel(const int* __restrict__ row, const int* __restrict__ col,
                               const float* __restrict__ ew, const float* __restrict__ dinv,
                               int* fill, int* srcs, float* coef, int ne) {
    int e = blockIdx.x * blockDim.x + threadIdx.x;
    if (e < ne) {
        int r = row[e], c = col[e];
        int pos = atomicAdd(&fill[c], 1);
        srcs[pos] = r;
        coef[pos] = dinv[r] * ew[e] * dinv[c];
    }
}

// ---------------- aggregation kernels ----------------

// 256-dim aggregation: one wave (64 lanes) per node, float4 per lane, 2-deep unroll.
__global__ __launch_bounds__(256) void agg256_kernel(
        const float* __restrict__ x, const float* __restrict__ dinv,
        const int* __restrict__ ptr, const int* __restrict__ srcs,
        const float* __restrict__ coef, float* __restrict__ out) {
    int wv = threadIdx.x >> 6, lane = threadIdx.x & 63;
    int node = blockIdx.x * 4 + wv;
    if (node >= N_NODES) return;
    const float4* x4 = (const float4*)x;
    float di = dinv[node];
    float s = di * di;
    float4 v = x4[node * 64 + lane];
    float ax = v.x * s, ay = v.y * s, az = v.z * s, aw = v.w * s;
    int j = ptr[node], e1 = ptr[node + 1];
    for (; j + 1 < e1; j += 2) {
        int s0 = srcs[j], s1 = srcs[j + 1];
        float c0 = coef[j], c1 = coef[j + 1];
        float4 u0 = x4[s0 * 64 + lane];
        float4 u1 = x4[s1 * 64 + lane];
        ax += c0 * u0.x + c1 * u1.x;
        ay += c0 * u0.y + c1 * u1.y;
        az += c0 * u0.z + c1 * u1.z;
        aw += c0 * u0.w + c1 * u1.w;
    }
    if (j < e1) {
        int s0 = srcs[j];
        float c0 = coef[j];
        float4 u0 = x4[s0 * 64 + lane];
        ax += c0 * u0.x; ay += c0 * u0.y; az += c0 * u0.z; aw += c0 * u0.w;
    }
    ((float4*)out)[node * 64 + lane] = make_float4(ax, ay, az, aw);
}

// 128-dim aggregation fused with +bias and PReLU: one wave per node, float2 per lane.
__global__ __launch_bounds__(256) void agg128_epi_kernel(
        const float* __restrict__ xw, const float* __restrict__ dinv,
        const int* __restrict__ ptr, const int* __restrict__ srcs,
        const float* __restrict__ coef, const float* __restrict__ b2,
        const float* __restrict__ alphap, float* __restrict__ out) {
    int wv = threadIdx.x >> 6, lane = threadIdx.x & 63;
    int node = blockIdx.x * 4 + wv;
    if (node >= N_NODES) return;
    const float2* x2 = (const float2*)xw;
    float di = dinv[node];
    float s = di * di;
    float2 v = x2[node * 64 + lane];
    float ax = v.x * s, ay = v.y * s;
    int j = ptr[node], e1 = ptr[node + 1];
    for (; j + 1 < e1; j += 2) {
        int s0 = srcs[j], s1 = srcs[j + 1];
        float c0 = coef[j], c1 = coef[j + 1];
        float2 u0 = x2[s0 * 64 + lane];
        float2 u1 = x2[s1 * 64 + lane];
        ax += c0 * u0.x + c1 * u1.x;
        ay += c0 * u0.y + c1 * u1.y;
    }
    if (j < e1) {
        int s0 = srcs[j];
        float c0 = coef[j];
        float2 u0 = x2[s0 * 64 + lane];
        ax += c0 * u0.x; ay += c0 * u0.y;
    }
    float alpha = alphap[0];
    float2 b = ((const float2*)b2)[lane];
    ax += b.x; ay += b.y;
    ax = (ax >= 0.f) ? ax : alpha * ax;
    ay = (ay >= 0.f) ? ay : alpha * ay;
    ((float2*)out)[node * 64 + lane] = make_float2(ax, ay);
}

// ---------------- fp32 tiled GEMM (128x128 tile, 256 threads, 8x8 per thread) ----------------
// C[M,N] = A[M,K] @ B[K,N]; EPI: += bias, PReLU(alpha). K,N multiples of 16/128; M guarded.

#define GBLK 128
#define GKS  16

template <bool EPI>
__global__ __launch_bounds__(256) void gemm128_kernel(
        const float* __restrict__ A, const float* __restrict__ B,
        const float* __restrict__ bias, const float* __restrict__ alphap,
        float* __restrict__ C, int M, int N, int K) {
    __shared__ float As[GKS][GBLK];   // [k][m] (transposed on store)
    __shared__ float Bs[GKS][GBLK];   // [k][n]
    int tid = threadIdx.x;
    int m0 = blockIdx.y * GBLK, n0 = blockIdx.x * GBLK;
    int tx = tid & 15, ty = tid >> 4;          // output: rows ty*8.., cols tx*8..

    int arow = tid >> 1, ak = (tid & 1) * 8;   // A loader: 128 rows x 16 k, 8 k per thread
    int brow = tid >> 4, bcol = (tid & 15) * 8;// B loader: 16 k x 128 n, 8 n per thread

    float acc[8][8];
#pragma unroll
    for (int i = 0; i < 8; ++i)
#pragma unroll
        for (int j = 0; j < 8; ++j) acc[i][j] = 0.f;

    for (int k0 = 0; k0 < K; k0 += GKS) {
        float4 av0 = make_float4(0.f, 0.f, 0.f, 0.f), av1 = av0;
        if (m0 + arow < M) {
            const float* ap = &A[(size_t)(m0 + arow) * K + k0 + ak];
            av0 = *(const float4*)ap;
            av1 = *(const float4*)(ap + 4);
        }
        As[ak + 0][arow] = av0.x; As[ak + 1][arow] = av0.y;
        As[ak + 2][arow] = av0.z; As[ak + 3][arow] = av0.w;
        As[ak + 4][arow] = av1.x; As[ak + 5][arow] = av1.y;
        As[ak + 6][arow] = av1.z; As[ak + 7][arow] = av1.w;
        {
            const float* bp = &B[(size_t)(k0 + brow) * N + n0 + bcol];
            *(float4*)&Bs[brow][bcol]     = *(const float4*)bp;
            *(float4*)&Bs[brow][bcol + 4] = *(const float4*)(bp + 4);
        }
        __syncthreads();
#pragma unroll
        for (int kk = 0; kk < GKS; ++kk) {
            float a[8], b[8];
            *(float4*)&a[0] = *(const float4*)&As[kk][ty * 8];
            *(float4*)&a[4] = *(const float4*)&As[kk][ty * 8 + 4];
            *(float4*)&b[0] = *(const float4*)&Bs[kk][tx * 8];
            *(float4*)&b[4] = *(const float4*)&Bs[kk][tx * 8 + 4];
#pragma unroll
            for (int i = 0; i < 8; ++i)
#pragma unroll
                for (int j = 0; j < 8; ++j) acc[i][j] = fmaf(a[i], b[j], acc[i][j]);
        }
        __syncthreads();
    }

    float alpha = EPI ? alphap[0] : 0.f;
#pragma unroll
    for (int i = 0; i < 8; ++i) {
        int m = m0 + ty * 8 + i;
        if (m < M) {
            float o[8];
#pragma unroll
            for (int j = 0; j < 8; ++j) {
                float v = acc[i][j];
                if (EPI) {
                    v += bias[n0 + tx * 8 + j];
                    v = (v >= 0.f) ? v : alpha * v;
                }
                o[j] = v;
            }
            *(float4*)&C[(size_t)m * N + n0 + tx * 8]     = *(const float4*)&o[0];
            *(float4*)&C[(size_t)m * N + n0 + tx * 8 + 4] = *(const float4*)&o[4];
        }
    }
}

// ---------------- launch ----------------

extern "C" void kernel_launch(void* const* d_in, const int* in_sizes, int n_in,
                              void* d_out, int out_size, void* d_ws, size_t ws_size,
                              hipStream_t stream) {
    const float* x     = (const float*)d_in[0];
    const float* eattr = (const float*)d_in[1];
    const float* W1    = (const float*)d_in[2];
    const float* b1    = (const float*)d_in[3];
    const float* W2    = (const float*)d_in[4];
    const float* b2    = (const float*)d_in[5];
    const float* alpha = (const float*)d_in[6];
    const int*   eidx  = (const int*)d_in[7];
    const int* row = eidx;
    const int* col = eidx + N_EDGES;
    float* out = (float*)d_out;

    // workspace layout (floats first, then ints); xw2 aliases aggx (dead by then)
    float* ws_f = (float*)d_ws;
    size_t off = 0;
    float* deg   = ws_f + off; off += N_NODES;
    float* dinv  = ws_f + off; off += N_NODES;
    float* coef  = ws_f + off; off += N_EDGES;
    float* aggx  = ws_f + off; off += (size_t)N_NODES * IN_DIM;   // 12.8M floats
    float* feat1 = ws_f + off; off += (size_t)N_NODES * H1;       // 25.6M floats
    float* xw2   = aggx;                                          // alias: aggx dead after gemm1
    int* cnt  = (int*)(ws_f + off); off += N_NODES;
    int* ptr  = (int*)(ws_f + off); off += N_NODES + 1;
    int* fill = (int*)(ws_f + off); off += N_NODES;
    int* part = (int*)(ws_f + off); off += N_NODES;
    int* bsum = (int*)(ws_f + off); off += 256;
    int* boff = (int*)(ws_f + off); off += 256;
    int* srcs = (int*)(ws_f + off); off += N_EDGES;

    const int nodeBlocks = (N_NODES + 255) / 256;   // 196
    const int edgeBlocks = (N_EDGES + 255) / 256;   // 3125

    // 1) CSR build + normalization coefficients
    init_kernel<<<nodeBlocks, 256, 0, stream>>>(deg, cnt, N_NODES);
    edge_deg_kernel<<<edgeBlocks, 256, 0, stream>>>(col, eattr, deg, cnt, N_EDGES);
    dinv_kernel<<<nodeBlocks, 256, 0, stream>>>(deg, dinv, N_NODES);
    scan_block_kernel<<<nodeBlocks, 256, 0, stream>>>(cnt, part, bsum, N_NODES);
    scan_tops_kernel<<<1, 256, 0, stream>>>(bsum, boff, nodeBlocks);
    scan_add_kernel<<<nodeBlocks, 256, 0, stream>>>(part, boff, ptr, fill, N_NODES);
    scatter_kernel<<<edgeBlocks, 256, 0, stream>>>(row, col, eattr, dinv, fill, srcs, coef, N_EDGES);

    // 2) layer 1: aggregate X (256-dim), then GEMM 256->512 + bias + PReLU
    agg256_kernel<<<(N_NODES + 3) / 4, 256, 0, stream>>>(x, dinv, ptr, srcs, coef, aggx);
    {
        dim3 grid(H1 / GBLK, (N_NODES + GBLK - 1) / GBLK);
        gemm128_kernel<true><<<grid, 256, 0, stream>>>(aggx, W1, b1, alpha, feat1, N_NODES, H1, IN_DIM);
    }

    // 3) layer 2: GEMM 512->128 first, then aggregate (128-dim) + bias + PReLU
    {
        dim3 grid(H2 / GBLK, (N_NODES + GBLK - 1) / GBLK);
        gemm128_kernel<false><<<grid, 256, 0, stream>>>(feat1, W2, nullptr, nullptr, xw2, N_NODES, H2, H1);
    }
    agg128_epi_kernel<<<(N_NODES + 3) / 4, 256, 0, stream>>>(xw2, dinv, ptr, srcs, coef, b2, alpha, out);
}

// Round 5
// 554.735 us; speedup vs baseline: 1.2363x; 1.2363x over previous
//
#include <hip/hip_runtime.h>

#define N_NODES 50000
#define N_EDGES 800000
#define IN_DIM  256
#define H1      512
#define H2      128

typedef __attribute__((ext_vector_type(8))) short  short8v;
typedef __attribute__((ext_vector_type(4))) float  float4v;
typedef __attribute__((ext_vector_type(4))) unsigned short ushort4v;

// split fp32 -> bf16 hi + bf16 lo (RNE both); v ~= hi + lo with ~16 mantissa bits
__device__ __forceinline__ void split_bf16(float v, unsigned short& h, unsigned short& l) {
    unsigned u = __builtin_bit_cast(unsigned, v);
    unsigned hr = (u + 0x7FFFu + ((u >> 16) & 1u)) >> 16;       // RNE to bf16
    float hf = __builtin_bit_cast(float, hr << 16);
    float lf = v - hf;
    unsigned ul = __builtin_bit_cast(unsigned, lf);
    unsigned lr = (ul + 0x7FFFu + ((ul >> 16) & 1u)) >> 16;
    h = (unsigned short)hr; l = (unsigned short)lr;
}

// ---------------- CSR build kernels ----------------

__global__ void init_kernel(float* deg, int* cnt, int n) {
    int i = blockIdx.x * blockDim.x + threadIdx.x;
    if (i < n) { deg[i] = 1.0f; cnt[i] = 0; }   // deg starts at 1.0 (self-loop weight)
}

__global__ void edge_deg_kernel(const int* __restrict__ col, const float* __restrict__ ew,
                                float* deg, int* cnt, int ne) {
    int e = blockIdx.x * blockDim.x + threadIdx.x;
    if (e < ne) {
        int c = col[e];
        atomicAdd(&deg[c], ew[e]);
        atomicAdd(&cnt[c], 1);
    }
}

__global__ void dinv_kernel(const float* __restrict__ deg, float* dinv, int n) {
    int i = blockIdx.x * blockDim.x + threadIdx.x;
    if (i < n) dinv[i] = rsqrtf(deg[i]);  // deg >= 1 always (self-loop)
}

// hierarchical exclusive scan: per-block scan -> top scan -> add offsets
__global__ void scan_block_kernel(const int* __restrict__ cnt, int* __restrict__ part,
                                  int* __restrict__ bsum, int n) {
    __shared__ int s[256];
    int tid = threadIdx.x;
    int i = blockIdx.x * 256 + tid;
    int v = (i < n) ? cnt[i] : 0;
    s[tid] = v; __syncthreads();
#pragma unroll
    for (int d = 1; d < 256; d <<= 1) {
        int t = (tid >= d) ? s[tid - d] : 0; __syncthreads();
        s[tid] += t; __syncthreads();
    }
    if (i < n) part[i] = s[tid] - v;           // exclusive within block
    if (tid == 255) bsum[blockIdx.x] = s[255]; // block total
}

__global__ void scan_tops_kernel(const int* __restrict__ bsum, int* __restrict__ boff, int nb) {
    __shared__ int s[256];
    int tid = threadIdx.x;
    int v = (tid < nb) ? bsum[tid] : 0;
    s[tid] = v; __syncthreads();
#pragma unroll
    for (int d = 1; d < 256; d <<= 1) {
        int t = (tid >= d) ? s[tid - d] : 0; __syncthreads();
        s[tid] += t; __syncthreads();
    }
    if (tid < nb) boff[tid] = s[tid] - v;      // exclusive across blocks
}

__global__ void scan_add_kernel(const int* __restrict__ part, const int* __restrict__ boff,
                                int* __restrict__ ptr, int* __restrict__ fill, int n) {
    int i = blockIdx.x * 256 + threadIdx.x;
    if (i < n) {
        int p = part[i] + boff[blockIdx.x];
        ptr[i] = p; fill[i] = p;
    }
    if (i == 0) ptr[n] = N_EDGES;              // total edges known at compile time
}

__global__ void scatter_kernel(const int* __restrict__ row, const int* __restrict__ col,
                               const float* __restrict__ ew, const float* __restrict__ dinv,
                               int* fill, int* srcs, float* coef, int ne) {
    int e = blockIdx.x * blockDim.x + threadIdx.x;
    if (e < ne) {
        int r = row[e], c = col[e];
        int pos = atomicAdd(&fill[c], 1);
        srcs[pos] = r;
        coef[pos] = dinv[r] * ew[e] * dinv[c];
    }
}

// weight convert: W [K][N] row-major fp32 -> Wt_hi/Wt_lo [N][K] bf16 planes
__global__ void convw_kernel(const float* __restrict__ W, unsigned short* __restrict__ Wh,
                             unsigned short* __restrict__ Wl, int K, int N) {
    int idx = blockIdx.x * 256 + threadIdx.x;
    if (idx < N * K) {
        int n = idx / K, k = idx % K;
        unsigned short h, l;
        split_bf16(W[(size_t)k * N + n], h, l);
        Wh[idx] = h; Wl[idx] = l;
    }
}

// ---------------- aggregation kernels ----------------

// 256-dim aggregation: one wave per node, float4 per lane; writes bf16 hi/lo planes.
__global__ __launch_bounds__(256) void agg256_kernel(
        const float* __restrict__ x, const float* __restrict__ dinv,
        const int* __restrict__ ptr, const int* __restrict__ srcs,
        const float* __restrict__ coef,
        unsigned short* __restrict__ out_h, unsigned short* __restrict__ out_l) {
    int wv = threadIdx.x >> 6, lane = threadIdx.x & 63;
    int node = blockIdx.x * 4 + wv;
    if (node >= N_NODES) return;
    const float4* x4 = (const float4*)x;
    float di = dinv[node];
    float s = di * di;
    float4 v = x4[node * 64 + lane];
    float ax = v.x * s, ay = v.y * s, az = v.z * s, aw = v.w * s;
    int j = ptr[node], e1 = ptr[node + 1];
    for (; j + 1 < e1; j += 2) {
        int s0 = srcs[j], s1 = srcs[j + 1];
        float c0 = coef[j], c1 = coef[j + 1];
        float4 u0 = x4[s0 * 64 + lane];
        float4 u1 = x4[s1 * 64 + lane];
        ax += c0 * u0.x + c1 * u1.x;
        ay += c0 * u0.y + c1 * u1.y;
        az += c0 * u0.z + c1 * u1.z;
        aw += c0 * u0.w + c1 * u1.w;
    }
    if (j < e1) {
        int s0 = srcs[j];
        float c0 = coef[j];
        float4 u0 = x4[s0 * 64 + lane];
        ax += c0 * u0.x; ay += c0 * u0.y; az += c0 * u0.z; aw += c0 * u0.w;
    }
    unsigned short hx, lx, hy, ly, hz, lz, hw, lw;
    split_bf16(ax, hx, lx);
    split_bf16(ay, hy, ly);
    split_bf16(az, hz, lz);
    split_bf16(aw, hw, lw);
    ushort4v h4 = {hx, hy, hz, hw};
    ushort4v l4 = {lx, ly, lz, lw};
    *(ushort4v*)(out_h + (size_t)node * IN_DIM + lane * 4) = h4;
    *(ushort4v*)(out_l + (size_t)node * IN_DIM + lane * 4) = l4;
}

// 128-dim aggregation fused with +bias and PReLU: one wave per node, float2 per lane.
__global__ __launch_bounds__(256) void agg128_epi_kernel(
        const float* __restrict__ xw, const float* __restrict__ dinv,
        const int* __restrict__ ptr, const int* __restrict__ srcs,
        const float* __restrict__ coef, const float* __restrict__ b2,
        const float* __restrict__ alphap, float* __restrict__ out) {
    int wv = threadIdx.x >> 6, lane = threadIdx.x & 63;
    int node = blockIdx.x * 4 + wv;
    if (node >= N_NODES) return;
    const float2* x2 = (const float2*)xw;
    float di = dinv[node];
    float s = di * di;
    float2 v = x2[node * 64 + lane];
    float ax = v.x * s, ay = v.y * s;
    int j = ptr[node], e1 = ptr[node + 1];
    for (; j + 1 < e1; j += 2) {
        int s0 = srcs[j], s1 = srcs[j + 1];
        float c0 = coef[j], c1 = coef[j + 1];
        float2 u0 = x2[s0 * 64 + lane];
        float2 u1 = x2[s1 * 64 + lane];
        ax += c0 * u0.x + c1 * u1.x;
        ay += c0 * u0.y + c1 * u1.y;
    }
    if (j < e1) {
        int s0 = srcs[j];
        float c0 = coef[j];
        float2 u0 = x2[s0 * 64 + lane];
        ax += c0 * u0.x; ay += c0 * u0.y;
    }
    float alpha = alphap[0];
    float2 b = ((const float2*)b2)[lane];
    ax += b.x; ay += b.y;
    ax = (ax >= 0.f) ? ax : alpha * ax;
    ay = (ay >= 0.f) ? ay : alpha * ay;
    ((float2*)out)[node * 64 + lane] = make_float2(ax, ay);
}

// ---------------- bf16x3 split MFMA GEMM ----------------
// C[M,N] = A[M,K] @ B[N,K]^T  with A,B given as bf16 hi/lo planes.
// A row-major [M][K]; B transposed [N][K]. 128x128 tile, 4 waves (2x2), BK=64.
// MODE 0: write fp32 C. MODE 1: +bias, PReLU, split to bf16 hi/lo planes.
// LDS [128][64] bf16 per plane with XOR swizzle (row&7)<<4 on byte offset (G4 recipe).

__device__ __forceinline__ int swz(int row, int k /*ushort idx, mult of 8*/) {
    return ((row << 7) + (k << 1)) ^ ((row & 7) << 4);
}

__device__ __forceinline__ void stage_plane(const unsigned short* __restrict__ g,
                                            unsigned short* l, int srow, int sk, bool ok) {
#pragma unroll
    for (int j = 0; j < 4; ++j) {
        short8v v = {0,0,0,0,0,0,0,0};
        if (ok) v = *(const short8v*)(g + sk + j * 8);
        *(short8v*)((char*)l + swz(srow, sk + j * 8)) = v;
    }
}

template <int MODE>
__global__ __launch_bounds__(256, 2) void gemm_mfma_kernel(
        const unsigned short* __restrict__ A_hi, const unsigned short* __restrict__ A_lo,
        const unsigned short* __restrict__ B_hi, const unsigned short* __restrict__ B_lo,
        const float* __restrict__ bias, const float* __restrict__ alphap,
        unsigned short* __restrict__ Oh, unsigned short* __restrict__ Ol,
        float* __restrict__ Of, int M, int N, int K) {
    __shared__ unsigned short smem[4][8192];   // Ah, Al, Bh, Bl planes: [128][64] each
    unsigned short* Ah = smem[0];
    unsigned short* Al = smem[1];
    unsigned short* Bh = smem[2];
    unsigned short* Bl = smem[3];

    const int tid  = threadIdx.x;
    const int lane = tid & 63, wave = tid >> 6;
    const int wm = wave >> 1, wn = wave & 1;
    const int lr = lane & 15, lk = (lane >> 4) << 3;
    const int srow = tid >> 1, sk = (tid & 1) << 5;

    const int m0 = blockIdx.y * 128, n0 = blockIdx.x * 128;

    float4v acc[4][4] = {};

    const bool arow_ok = (m0 + srow) < M;
    const unsigned short* gAh = A_hi + (size_t)(m0 + srow) * K;
    const unsigned short* gAl = A_lo + (size_t)(m0 + srow) * K;
    const unsigned short* gBh = B_hi + (size_t)(n0 + srow) * K;
    const unsigned short* gBl = B_lo + (size_t)(n0 + srow) * K;

    for (int k0 = 0; k0 < K; k0 += 64) {
        stage_plane(gAh + k0, Ah, srow, sk, arow_ok);
        stage_plane(gAl + k0, Al, srow, sk, arow_ok);
        stage_plane(gBh + k0, Bh, srow, sk, true);
        stage_plane(gBl + k0, Bl, srow, sk, true);
        __syncthreads();
#pragma unroll
        for (int q = 0; q < 2; ++q) {
            short8v ah[4], al[4], bh[4], bl[4];
#pragma unroll
            for (int i = 0; i < 4; ++i) {
                ah[i] = *(const short8v*)((const char*)Ah + swz(wm * 64 + i * 16 + lr, q * 32 + lk));
                al[i] = *(const short8v*)((const char*)Al + swz(wm * 64 + i * 16 + lr, q * 32 + lk));
                bh[i] = *(const short8v*)((const char*)Bh + swz(wn * 64 + i * 16 + lr, q * 32 + lk));
                bl[i] = *(const short8v*)((const char*)Bl + swz(wn * 64 + i * 16 + lr, q * 32 + lk));
            }
#pragma unroll
            for (int mi = 0; mi < 4; ++mi)
#pragma unroll
                for (int ni = 0; ni < 4; ++ni) {
                    acc[mi][ni] = __builtin_amdgcn_mfma_f32_16x16x32_bf16(ah[mi], bh[ni], acc[mi][ni], 0, 0, 0);
                    acc[mi][ni] = __builtin_amdgcn_mfma_f32_16x16x32_bf16(ah[mi], bl[ni], acc[mi][ni], 0, 0, 0);
                    acc[mi][ni] = __builtin_amdgcn_mfma_f32_16x16x32_bf16(al[mi], bh[ni], acc[mi][ni], 0, 0, 0);
                }
        }
        __syncthreads();
    }

    const float alpha = (MODE == 1) ? alphap[0] : 0.f;
#pragma unroll
    for (int mi = 0; mi < 4; ++mi) {
        int grow_base = m0 + wm * 64 + mi * 16 + (lane >> 4) * 4;
#pragma unroll
        for (int ni = 0; ni < 4; ++ni) {
            int gcol = n0 + wn * 64 + ni * 16 + lr;
#pragma unroll
            for (int r = 0; r < 4; ++r) {
                int grow = grow_base + r;
                if (grow < M) {
                    float v = acc[mi][ni][r];
                    if (MODE == 1) {
                        v += bias[gcol];
                        v = (v >= 0.f) ? v : alpha * v;
                        unsigned short h, l;
                        split_bf16(v, h, l);
                        Oh[(size_t)grow * N + gcol] = h;
                        Ol[(size_t)grow * N + gcol] = l;
                    } else {
                        Of[(size_t)grow * N + gcol] = v;
                    }
                }
            }
        }
    }
}

// ---------------- launch ----------------

extern "C" void kernel_launch(void* const* d_in, const int* in_sizes, int n_in,
                              void* d_out, int out_size, void* d_ws, size_t ws_size,
                              hipStream_t stream) {
    const float* x     = (const float*)d_in[0];
    const float* eattr = (const float*)d_in[1];
    const float* W1    = (const float*)d_in[2];
    const float* b1    = (const float*)d_in[3];
    const float* W2    = (const float*)d_in[4];
    const float* b2    = (const float*)d_in[5];
    const float* alpha = (const float*)d_in[6];
    const int*   eidx  = (const int*)d_in[7];
    const int* row = eidx;
    const int* col = eidx + N_EDGES;
    float* out = (float*)d_out;

    // workspace layout (4B units); xw2 aliases aggx_h region (dead after gemm1)
    float* ws_f = (float*)d_ws;
    size_t off = 0;
    float* deg   = ws_f + off; off += N_NODES;
    float* dinv  = ws_f + off; off += N_NODES;
    float* coef  = ws_f + off; off += N_EDGES;
    unsigned short* aggx_h = (unsigned short*)(ws_f + off); off += (size_t)N_NODES * IN_DIM / 2; // bf16 plane
    unsigned short* aggx_l = (unsigned short*)(ws_f + off); off += (size_t)N_NODES * IN_DIM / 2;
    float* xw2 = (float*)aggx_h;  // 6.4M floats, fits in aggx_h plane region (dead after gemm1)
    unsigned short* feat1_h = (unsigned short*)(ws_f + off); off += (size_t)N_NODES * H1 / 2;
    unsigned short* feat1_l = (unsigned short*)(ws_f + off); off += (size_t)N_NODES * H1 / 2;
    unsigned short* W1t_h = (unsigned short*)(ws_f + off); off += (size_t)IN_DIM * H1 / 2;
    unsigned short* W1t_l = (unsigned short*)(ws_f + off); off += (size_t)IN_DIM * H1 / 2;
    unsigned short* W2t_h = (unsigned short*)(ws_f + off); off += (size_t)H1 * H2 / 2;
    unsigned short* W2t_l = (unsigned short*)(ws_f + off); off += (size_t)H1 * H2 / 2;
    int* cnt  = (int*)(ws_f + off); off += N_NODES;
    int* ptr  = (int*)(ws_f + off); off += N_NODES + 1;
    int* fill = (int*)(ws_f + off); off += N_NODES;
    int* part = (int*)(ws_f + off); off += N_NODES;
    int* bsum = (int*)(ws_f + off); off += 256;
    int* boff = (int*)(ws_f + off); off += 256;
    int* srcs = (int*)(ws_f + off); off += N_EDGES;

    const int nodeBlocks = (N_NODES + 255) / 256;   // 196
    const int edgeBlocks = (N_EDGES + 255) / 256;   // 3125

    // 0) weight conversion (tiny)
    convw_kernel<<<(IN_DIM * H1 + 255) / 256, 256, 0, stream>>>(W1, W1t_h, W1t_l, IN_DIM, H1);
    convw_kernel<<<(H1 * H2 + 255) / 256, 256, 0, stream>>>(W2, W2t_h, W2t_l, H1, H2);

    // 1) CSR build + normalization coefficients
    init_kernel<<<nodeBlocks, 256, 0, stream>>>(deg, cnt, N_NODES);
    edge_deg_kernel<<<edgeBlocks, 256, 0, stream>>>(col, eattr, deg, cnt, N_EDGES);
    dinv_kernel<<<nodeBlocks, 256, 0, stream>>>(deg, dinv, N_NODES);
    scan_block_kernel<<<nodeBlocks, 256, 0, stream>>>(cnt, part, bsum, N_NODES);
    scan_tops_kernel<<<1, 256, 0, stream>>>(bsum, boff, nodeBlocks);
    scan_add_kernel<<<nodeBlocks, 256, 0, stream>>>(part, boff, ptr, fill, N_NODES);
    scatter_kernel<<<edgeBlocks, 256, 0, stream>>>(row, col, eattr, dinv, fill, srcs, coef, N_EDGES);

    // 2) layer 1: aggregate X (256-dim) -> bf16 hi/lo, then MFMA GEMM 256->512 + bias + PReLU
    agg256_kernel<<<(N_NODES + 3) / 4, 256, 0, stream>>>(x, dinv, ptr, srcs, coef, aggx_h, aggx_l);
    {
        dim3 grid(H1 / 128, (N_NODES + 127) / 128);   // (4, 391)
        gemm_mfma_kernel<1><<<grid, 256, 0, stream>>>(aggx_h, aggx_l, W1t_h, W1t_l,
                                                      b1, alpha, feat1_h, feat1_l, nullptr,
                                                      N_NODES, H1, IN_DIM);
    }

    // 3) layer 2: MFMA GEMM 512->128 (fp32 out), then aggregate (128-dim) + bias + PReLU
    {
        dim3 grid(H2 / 128, (N_NODES + 127) / 128);   // (1, 391)
        gemm_mfma_kernel<0><<<grid, 256, 0, stream>>>(feat1_h, feat1_l, W2t_h, W2t_l,
                                                      nullptr, nullptr, nullptr, nullptr, xw2,
                                                      N_NODES, H2, H1);
    }
    agg128_epi_kernel<<<(N_NODES + 3) / 4, 256, 0, stream>>>(xw2, dinv, ptr, srcs, coef, b2, alpha, out);
}

// Round 7
// 525.190 us; speedup vs baseline: 1.3059x; 1.0563x over previous
//
#include <hip/hip_runtime.h>

#define N_NODES 50000
#define N_EDGES 800000
#define IN_DIM  256
#define H1      512
#define H2      128

typedef __attribute__((ext_vector_type(8))) short  short8v;
typedef __attribute__((ext_vector_type(4))) float  float4v;
typedef __attribute__((ext_vector_type(4))) unsigned short ushort4v;

// split fp32 -> bf16 hi + bf16 lo (RNE both); v ~= hi + lo with ~16 mantissa bits
__device__ __forceinline__ void split_bf16(float v, unsigned short& h, unsigned short& l) {
    unsigned u = __builtin_bit_cast(unsigned, v);
    unsigned hr = (u + 0x7FFFu + ((u >> 16) & 1u)) >> 16;       // RNE to bf16
    float hf = __builtin_bit_cast(float, hr << 16);
    float lf = v - hf;
    unsigned ul = __builtin_bit_cast(unsigned, lf);
    unsigned lr = (ul + 0x7FFFu + ((ul >> 16) & 1u)) >> 16;
    h = (unsigned short)hr; l = (unsigned short)lr;
}

// ---------------- CSR build kernels ----------------

__global__ void init_kernel(float* deg, int* cnt, int n) {
    int i = blockIdx.x * blockDim.x + threadIdx.x;
    if (i < n) { deg[i] = 1.0f; cnt[i] = 0; }   // deg starts at 1.0 (self-loop weight)
}

__global__ void edge_deg_kernel(const int* __restrict__ col, const float* __restrict__ ew,
                                float* deg, int* cnt, int ne) {
    int e = blockIdx.x * blockDim.x + threadIdx.x;
    if (e < ne) {
        int c = col[e];
        atomicAdd(&deg[c], ew[e]);
        atomicAdd(&cnt[c], 1);
    }
}

__global__ void dinv_kernel(const float* __restrict__ deg, float* dinv, int n) {
    int i = blockIdx.x * blockDim.x + threadIdx.x;
    if (i < n) dinv[i] = rsqrtf(deg[i]);  // deg >= 1 always (self-loop)
}

// hierarchical exclusive scan: per-block scan -> top scan -> add offsets
__global__ void scan_block_kernel(const int* __restrict__ cnt, int* __restrict__ part,
                                  int* __restrict__ bsum, int n) {
    __shared__ int s[256];
    int tid = threadIdx.x;
    int i = blockIdx.x * 256 + tid;
    int v = (i < n) ? cnt[i] : 0;
    s[tid] = v; __syncthreads();
#pragma unroll
    for (int d = 1; d < 256; d <<= 1) {
        int t = (tid >= d) ? s[tid - d] : 0; __syncthreads();
        s[tid] += t; __syncthreads();
    }
    if (i < n) part[i] = s[tid] - v;           // exclusive within block
    if (tid == 255) bsum[blockIdx.x] = s[255]; // block total
}

__global__ void scan_tops_kernel(const int* __restrict__ bsum, int* __restrict__ boff, int nb) {
    __shared__ int s[256];
    int tid = threadIdx.x;
    int v = (tid < nb) ? bsum[tid] : 0;
    s[tid] = v; __syncthreads();
#pragma unroll
    for (int d = 1; d < 256; d <<= 1) {
        int t = (tid >= d) ? s[tid - d] : 0; __syncthreads();
        s[tid] += t; __syncthreads();
    }
    if (tid < nb) boff[tid] = s[tid] - v;      // exclusive across blocks
}

__global__ void scan_add_kernel(const int* __restrict__ part, const int* __restrict__ boff,
                                int* __restrict__ ptr, int* __restrict__ fill, int n) {
    int i = blockIdx.x * 256 + threadIdx.x;
    if (i < n) {
        int p = part[i] + boff[blockIdx.x];
        ptr[i] = p; fill[i] = p;
    }
    if (i == 0) ptr[n] = N_EDGES;              // total edges known at compile time
}

// packed edge record: .x = src node, .y = coef bits (one 8B store/load per edge)
__global__ void scatter_kernel(const int* __restrict__ row, const int* __restrict__ col,
                               const float* __restrict__ ew, const float* __restrict__ dinv,
                               int* fill, int2* __restrict__ edges, int ne) {
    int e = blockIdx.x * blockDim.x + threadIdx.x;
    if (e < ne) {
        int r = row[e], c = col[e];
        int pos = atomicAdd(&fill[c], 1);
        float w = dinv[r] * ew[e] * dinv[c];
        edges[pos] = make_int2(r, __float_as_int(w));
    }
}

// weight convert: W [K][N] row-major fp32 -> Wt_hi/Wt_lo [N][K] bf16 planes
__global__ void convw_kernel(const float* __restrict__ W, unsigned short* __restrict__ Wh,
                             unsigned short* __restrict__ Wl, int K, int N) {
    int idx = blockIdx.x * 256 + threadIdx.x;
    if (idx < N * K) {
        int n = idx / K, k = idx % K;
        unsigned short h, l;
        split_bf16(W[(size_t)k * N + n], h, l);
        Wh[idx] = h; Wl[idx] = l;
    }
}

// ---------------- aggregation kernels ----------------

// 256-dim aggregation: one wave per node, float4 per lane, 4-deep unroll (MLP);
// writes bf16 hi/lo planes for the MFMA GEMM.
__global__ __launch_bounds__(256) void agg256_kernel(
        const float* __restrict__ x, const float* __restrict__ dinv,
        const int* __restrict__ ptr, const int2* __restrict__ edges,
        unsigned short* __restrict__ out_h, unsigned short* __restrict__ out_l) {
    int wv = threadIdx.x >> 6, lane = threadIdx.x & 63;
    int node = blockIdx.x * 4 + wv;
    if (node >= N_NODES) return;
    const float4* x4 = (const float4*)x;
    float di = dinv[node];
    float s = di * di;
    float4 v = x4[node * 64 + lane];
    float ax = v.x * s, ay = v.y * s, az = v.z * s, aw = v.w * s;
    int j = ptr[node], e1 = ptr[node + 1];
    for (; j + 3 < e1; j += 4) {
        int2 e0 = edges[j], e1_ = edges[j + 1], e2 = edges[j + 2], e3 = edges[j + 3];
        float4 u0 = x4[e0.x * 64 + lane];
        float4 u1 = x4[e1_.x * 64 + lane];
        float4 u2 = x4[e2.x * 64 + lane];
        float4 u3 = x4[e3.x * 64 + lane];
        float c0 = __int_as_float(e0.y), c1 = __int_as_float(e1_.y);
        float c2 = __int_as_float(e2.y), c3 = __int_as_float(e3.y);
        ax += c0 * u0.x + c1 * u1.x + c2 * u2.x + c3 * u3.x;
        ay += c0 * u0.y + c1 * u1.y + c2 * u2.y + c3 * u3.y;
        az += c0 * u0.z + c1 * u1.z + c2 * u2.z + c3 * u3.z;
        aw += c0 * u0.w + c1 * u1.w + c2 * u2.w + c3 * u3.w;
    }
    for (; j < e1; ++j) {
        int2 e0 = edges[j];
        float c0 = __int_as_float(e0.y);
        float4 u0 = x4[e0.x * 64 + lane];
        ax += c0 * u0.x; ay += c0 * u0.y; az += c0 * u0.z; aw += c0 * u0.w;
    }
    unsigned short hx, lx, hy, ly, hz, lz, hw, lw;
    split_bf16(ax, hx, lx);
    split_bf16(ay, hy, ly);
    split_bf16(az, hz, lz);
    split_bf16(aw, hw, lw);
    ushort4v h4 = {hx, hy, hz, hw};
    ushort4v l4 = {lx, ly, lz, lw};
    *(ushort4v*)(out_h + (size_t)node * IN_DIM + lane * 4) = h4;
    *(ushort4v*)(out_l + (size_t)node * IN_DIM + lane * 4) = l4;
}

// 128-dim aggregation fused with +bias and PReLU: one wave per node, float2 per lane.
__global__ __launch_bounds__(256) void agg128_epi_kernel(
        const float* __restrict__ xw, const float* __restrict__ dinv,
        const int* __restrict__ ptr, const int2* __restrict__ edges,
        const float* __restrict__ b2, const float* __restrict__ alphap,
        float* __restrict__ out) {
    int wv = threadIdx.x >> 6, lane = threadIdx.x & 63;
    int node = blockIdx.x * 4 + wv;
    if (node >= N_NODES) return;
    const float2* x2 = (const float2*)xw;
    float di = dinv[node];
    float s = di * di;
    float2 v = x2[node * 64 + lane];
    float ax = v.x * s, ay = v.y * s;
    int j = ptr[node], e1 = ptr[node + 1];
    for (; j + 3 < e1; j += 4) {
        int2 e0 = edges[j], e1_ = edges[j + 1], e2 = edges[j + 2], e3 = edges[j + 3];
        float2 u0 = x2[e0.x * 64 + lane];
        float2 u1 = x2[e1_.x * 64 + lane];
        float2 u2 = x2[e2.x * 64 + lane];
        float2 u3 = x2[e3.x * 64 + lane];
        float c0 = __int_as_float(e0.y), c1 = __int_as_float(e1_.y);
        float c2 = __int_as_float(e2.y), c3 = __int_as_float(e3.y);
        ax += c0 * u0.x + c1 * u1.x + c2 * u2.x + c3 * u3.x;
        ay += c0 * u0.y + c1 * u1.y + c2 * u2.y + c3 * u3.y;
    }
    for (; j < e1; ++j) {
        int2 e0 = edges[j];
        float c0 = __int_as_float(e0.y);
        float2 u0 = x2[e0.x * 64 + lane];
        ax += c0 * u0.x; ay += c0 * u0.y;
    }
    float alpha = alphap[0];
    float2 b = ((const float2*)b2)[lane];
    ax += b.x; ay += b.y;
    ax = (ax >= 0.f) ? ax : alpha * ax;
    ay = (ay >= 0.f) ? ay : alpha * ay;
    ((float2*)out)[node * 64 + lane] = make_float2(ax, ay);
}

// ---------------- bf16x3 split MFMA GEMM ----------------
// C[M,N] = A[M,K] @ B[N,K]^T  with A,B given as bf16 hi/lo planes.
// 128x128 tile, 4 waves (2x2), BK=64. Staging via global_load_lds width-16:
// LDS is LINEAR [128][64]; the XOR swizzle ((row&7)<<4 on bytes) is applied by
// PRE-SWIZZLING the global source k-offset (rule 21: linear dest + inverse-swz
// source + swz on read). ds_read side uses swz() exactly as before.

__device__ __forceinline__ int swz(int row, int k /*ushort idx, mult of 8*/) {
    return ((row << 7) + (k << 1)) ^ ((row & 7) << 4);
}

__device__ __forceinline__ void gload16(const void* g, void* l) {
    __builtin_amdgcn_global_load_lds(
        (const __attribute__((address_space(1))) unsigned int*)g,
        (__attribute__((address_space(3))) unsigned int*)l, 16, 0, 0);
}

// stage one [128][64] bf16 plane; wave w covers rows [w*32, w*32+32)
__device__ __forceinline__ void stage_plane_async(
        const unsigned short* __restrict__ gbase,  // plane, row-major [*][K]
        unsigned short* lds, int K, int grow0, int k0, int wave, int lane) {
    int r8 = lane >> 3;                 // row within 8-row group == row&7 of lds row
    int kk = k0 + (((lane & 7) ^ r8) << 3);   // inverse-swizzled k (units of 8 bf16 = 16B)
#pragma unroll
    for (int t = 0; t < 4; ++t) {
        int rowblk = wave * 32 + t * 8;
        const unsigned short* g = gbase + (size_t)(grow0 + rowblk + r8) * K + kk;
        gload16(g, lds + (size_t)rowblk * 64);  // wave-uniform base; HW adds lane*16B
    }
}

template <int MODE>
__global__ __launch_bounds__(256, 2) void gemm_mfma_kernel(
        const unsigned short* __restrict__ A_hi, const unsigned short* __restrict__ A_lo,
        const unsigned short* __restrict__ B_hi, const unsigned short* __restrict__ B_lo,
        const float* __restrict__ bias, const float* __restrict__ alphap,
        unsigned short* __restrict__ Oh, unsigned short* __restrict__ Ol,
        float* __restrict__ Of, int M, int N, int K) {
    __shared__ unsigned short smem[4][8192];   // Ah, Al, Bh, Bl planes: [128][64] each
    unsigned short* Ah = smem[0];
    unsigned short* Al = smem[1];
    unsigned short* Bh = smem[2];
    unsigned short* Bl = smem[3];

    const int tid  = threadIdx.x;
    const int lane = tid & 63, wave = tid >> 6;
    const int wm = wave >> 1, wn = wave & 1;
    const int lr = lane & 15, lk = (lane >> 4) << 3;

    const int m0 = blockIdx.y * 128, n0 = blockIdx.x * 128;

    float4v acc[4][4] = {};

    for (int k0 = 0; k0 < K; k0 += 64) {
        // A-tail rows (m0+row >= M) read garbage from adjacent ws regions: finite,
        // discarded by the guarded store below.
        stage_plane_async(A_hi, Ah, K, m0, k0, wave, lane);
        stage_plane_async(A_lo, Al, K, m0, k0, wave, lane);
        stage_plane_async(B_hi, Bh, K, n0, k0, wave, lane);
        stage_plane_async(B_lo, Bl, K, n0, k0, wave, lane);
        __syncthreads();   // drains vmcnt -> LDS tiles complete
#pragma unroll
        for (int q = 0; q < 2; ++q) {
            short8v ah[4], al[4], bh[4], bl[4];
#pragma unroll
            for (int i = 0; i < 4; ++i) {
                ah[i] = *(const short8v*)((const char*)Ah + swz(wm * 64 + i * 16 + lr, q * 32 + lk));
                al[i] = *(const short8v*)((const char*)Al + swz(wm * 64 + i * 16 + lr, q * 32 + lk));
                bh[i] = *(const short8v*)((const char*)Bh + swz(wn * 64 + i * 16 + lr, q * 32 + lk));
                bl[i] = *(const short8v*)((const char*)Bl + swz(wn * 64 + i * 16 + lr, q * 32 + lk));
            }
#pragma unroll
            for (int mi = 0; mi < 4; ++mi)
#pragma unroll
                for (int ni = 0; ni < 4; ++ni) {
                    acc[mi][ni] = __builtin_amdgcn_mfma_f32_16x16x32_bf16(ah[mi], bh[ni], acc[mi][ni], 0, 0, 0);
                    acc[mi][ni] = __builtin_amdgcn_mfma_f32_16x16x32_bf16(ah[mi], bl[ni], acc[mi][ni], 0, 0, 0);
                    acc[mi][ni] = __builtin_amdgcn_mfma_f32_16x16x32_bf16(al[mi], bh[ni], acc[mi][ni], 0, 0, 0);
                }
        }
        __syncthreads();
    }

    const float alpha = (MODE == 1) ? alphap[0] : 0.f;
#pragma unroll
    for (int mi = 0; mi < 4; ++mi) {
        int grow_base = m0 + wm * 64 + mi * 16 + (lane >> 4) * 4;
#pragma unroll
        for (int ni = 0; ni < 4; ++ni) {
            int gcol = n0 + wn * 64 + ni * 16 + lr;
#pragma unroll
            for (int r = 0; r < 4; ++r) {
                int grow = grow_base + r;
                if (grow < M) {
                    float v = acc[mi][ni][r];
                    if (MODE == 1) {
                        v += bias[gcol];
                        v = (v >= 0.f) ? v : alpha * v;
                        unsigned short h, l;
                        split_bf16(v, h, l);
                        Oh[(size_t)grow * N + gcol] = h;
                        Ol[(size_t)grow * N + gcol] = l;
                    } else {
                        Of[(size_t)grow * N + gcol] = v;
                    }
                }
            }
        }
    }
}

// ---------------- launch ----------------

extern "C" void kernel_launch(void* const* d_in, const int* in_sizes, int n_in,
                              void* d_out, int out_size, void* d_ws, size_t ws_size,
                              hipStream_t stream) {
    const float* x     = (const float*)d_in[0];
    const float* eattr = (const float*)d_in[1];
    const float* W1    = (const float*)d_in[2];
    const float* b1    = (const float*)d_in[3];
    const float* W2    = (const float*)d_in[4];
    const float* b2    = (const float*)d_in[5];
    const float* alpha = (const float*)d_in[6];
    const int*   eidx  = (const int*)d_in[7];
    const int* row = eidx;
    const int* col = eidx + N_EDGES;
    float* out = (float*)d_out;

    // workspace layout (4B units); xw2 aliases aggx_h region (dead after gemm1)
    float* ws_f = (float*)d_ws;
    size_t off = 0;
    float* deg   = ws_f + off; off += N_NODES;
    float* dinv  = ws_f + off; off += N_NODES;
    int2*  edges = (int2*)(ws_f + off); off += (size_t)2 * N_EDGES;   // packed (src, coef)
    unsigned short* aggx_h = (unsigned short*)(ws_f + off); off += (size_t)N_NODES * IN_DIM / 2; // bf16 plane
    unsigned short* aggx_l = (unsigned short*)(ws_f + off); off += (size_t)N_NODES * IN_DIM / 2;
    float* xw2 = (float*)aggx_h;  // 6.4M floats, fits in aggx_h plane region (dead after gemm1)
    unsigned short* feat1_h = (unsigned short*)(ws_f + off); off += (size_t)N_NODES * H1 / 2;
    unsigned short* feat1_l = (unsigned short*)(ws_f + off); off += (size_t)N_NODES * H1 / 2;
    unsigned short* W1t_h = (unsigned short*)(ws_f + off); off += (size_t)IN_DIM * H1 / 2;
    unsigned short* W1t_l = (unsigned short*)(ws_f + off); off += (size_t)IN_DIM * H1 / 2;
    unsigned short* W2t_h = (unsigned short*)(ws_f + off); off += (size_t)H1 * H2 / 2;
    unsigned short* W2t_l = (unsigned short*)(ws_f + off); off += (size_t)H1 * H2 / 2;
    int* cnt  = (int*)(ws_f + off); off += N_NODES;
    int* ptr  = (int*)(ws_f + off); off += N_NODES + 1;
    int* fill = (int*)(ws_f + off); off += N_NODES;
    int* part = (int*)(ws_f + off); off += N_NODES;
    int* bsum = (int*)(ws_f + off); off += 256;
    int* boff = (int*)(ws_f + off); off += 256;

    const int nodeBlocks = (N_NODES + 255) / 256;   // 196
    const int edgeBlocks = (N_EDGES + 255) / 256;   // 3125

    // 0) weight conversion (tiny)
    convw_kernel<<<(IN_DIM * H1 + 255) / 256, 256, 0, stream>>>(W1, W1t_h, W1t_l, IN_DIM, H1);
    convw_kernel<<<(H1 * H2 + 255) / 256, 256, 0, stream>>>(W2, W2t_h, W2t_l, H1, H2);

    // 1) CSR build + normalization coefficients
    init_kernel<<<nodeBlocks, 256, 0, stream>>>(deg, cnt, N_NODES);
    edge_deg_kernel<<<edgeBlocks, 256, 0, stream>>>(col, eattr, deg, cnt, N_EDGES);
    dinv_kernel<<<nodeBlocks, 256, 0, stream>>>(deg, dinv, N_NODES);
    scan_block_kernel<<<nodeBlocks, 256, 0, stream>>>(cnt, part, bsum, N_NODES);
    scan_tops_kernel<<<1, 256, 0, stream>>>(bsum, boff, nodeBlocks);
    scan_add_kernel<<<nodeBlocks, 256, 0, stream>>>(part, boff, ptr, fill, N_NODES);
    scatter_kernel<<<edgeBlocks, 256, 0, stream>>>(row, col, eattr, dinv, fill, edges, N_EDGES);

    // 2) layer 1: aggregate X (256-dim) -> bf16 hi/lo, then MFMA GEMM 256->512 + bias + PReLU
    agg256_kernel<<<(N_NODES + 3) / 4, 256, 0, stream>>>(x, dinv, ptr, edges, aggx_h, aggx_l);
    {
        dim3 grid(H1 / 128, (N_NODES + 127) / 128);   // (4, 391)
        gemm_mfma_kernel<1><<<grid, 256, 0, stream>>>(aggx_h, aggx_l, W1t_h, W1t_l,
                                                      b1, alpha, feat1_h, feat1_l, nullptr,
                                                      N_NODES, H1, IN_DIM);
    }

    // 3) layer 2: MFMA GEMM 512->128 (fp32 out), then aggregate (128-dim) + bias + PReLU
    {
        dim3 grid(H2 / 128, (N_NODES + 127) / 128);   // (1, 391)
        gemm_mfma_kernel<0><<<grid, 256, 0, stream>>>(feat1_h, feat1_l, W2t_h, W2t_l,
                                                      nullptr, nullptr, nullptr, nullptr, xw2,
                                                      N_NODES, H2, H1);
    }
    agg128_epi_kernel<<<(N_NODES + 3) / 4, 256, 0, stream>>>(xw2, dinv, ptr, edges, b2, alpha, out);
}

// Round 8
// 519.121 us; speedup vs baseline: 1.3211x; 1.0117x over previous
//
#include <hip/hip_runtime.h>

#define N_NODES 50000
#define N_EDGES 800000
#define IN_DIM  256
#define H1      512
#define H2      128

typedef __attribute__((ext_vector_type(8))) short  short8v;
typedef __attribute__((ext_vector_type(4))) float  float4v;

// split fp32 -> bf16 hi + bf16 lo (RNE both); v ~= hi + lo with ~16 mantissa bits
__device__ __forceinline__ void split_bf16(float v, unsigned short& h, unsigned short& l) {
    unsigned u = __builtin_bit_cast(unsigned, v);
    unsigned hr = (u + 0x7FFFu + ((u >> 16) & 1u)) >> 16;       // RNE to bf16
    float hf = __builtin_bit_cast(float, hr << 16);
    float lf = v - hf;
    unsigned ul = __builtin_bit_cast(unsigned, lf);
    unsigned lr = (ul + 0x7FFFu + ((ul >> 16) & 1u)) >> 16;
    h = (unsigned short)hr; l = (unsigned short)lr;
}

// ---------------- CSR build kernels ----------------

__global__ void init_kernel(float* deg, int* cnt, int n) {
    int i = blockIdx.x * blockDim.x + threadIdx.x;
    if (i < n) { deg[i] = 1.0f; cnt[i] = 0; }   // deg starts at 1.0 (self-loop weight)
}

__global__ void edge_deg_kernel(const int* __restrict__ col, const float* __restrict__ ew,
                                float* deg, int* cnt, int ne) {
    int e = blockIdx.x * blockDim.x + threadIdx.x;
    if (e < ne) {
        int c = col[e];
        atomicAdd(&deg[c], ew[e]);
        atomicAdd(&cnt[c], 1);
    }
}

__global__ void dinv_kernel(const float* __restrict__ deg, float* dinv, int n) {
    int i = blockIdx.x * blockDim.x + threadIdx.x;
    if (i < n) dinv[i] = rsqrtf(deg[i]);  // deg >= 1 always (self-loop)
}

// hierarchical exclusive scan: per-block scan -> top scan -> add offsets
__global__ void scan_block_kernel(const int* __restrict__ cnt, int* __restrict__ part,
                                  int* __restrict__ bsum, int n) {
    __shared__ int s[256];
    int tid = threadIdx.x;
    int i = blockIdx.x * 256 + tid;
    int v = (i < n) ? cnt[i] : 0;
    s[tid] = v; __syncthreads();
#pragma unroll
    for (int d = 1; d < 256; d <<= 1) {
        int t = (tid >= d) ? s[tid - d] : 0; __syncthreads();
        s[tid] += t; __syncthreads();
    }
    if (i < n) part[i] = s[tid] - v;           // exclusive within block
    if (tid == 255) bsum[blockIdx.x] = s[255]; // block total
}

__global__ void scan_tops_kernel(const int* __restrict__ bsum, int* __restrict__ boff, int nb) {
    __shared__ int s[256];
    int tid = threadIdx.x;
    int v = (tid < nb) ? bsum[tid] : 0;
    s[tid] = v; __syncthreads();
#pragma unroll
    for (int d = 1; d < 256; d <<= 1) {
        int t = (tid >= d) ? s[tid - d] : 0; __syncthreads();
        s[tid] += t; __syncthreads();
    }
    if (tid < nb) boff[tid] = s[tid] - v;      // exclusive across blocks
}

__global__ void scan_add_kernel(const int* __restrict__ part, const int* __restrict__ boff,
                                int* __restrict__ ptr, int* __restrict__ fill, int n) {
    int i = blockIdx.x * 256 + threadIdx.x;
    if (i < n) {
        int p = part[i] + boff[blockIdx.x];
        ptr[i] = p; fill[i] = p;
    }
    if (i == 0) ptr[n] = N_EDGES;              // total edges known at compile time
}

// packed edge record: .x = src node, .y = coef bits (one 8B store/load per edge)
__global__ void scatter_kernel(const int* __restrict__ row, const int* __restrict__ col,
                               const float* __restrict__ ew, const float* __restrict__ dinv,
                               int* fill, int2* __restrict__ edges, int ne) {
    int e = blockIdx.x * blockDim.x + threadIdx.x;
    if (e < ne) {
        int r = row[e], c = col[e];
        int pos = atomicAdd(&fill[c], 1);
        float w = dinv[r] * ew[e] * dinv[c];
        edges[pos] = make_int2(r, __float_as_int(w));
    }
}

// weight convert: W [K][N] row-major fp32 -> Wt_hi/Wt_lo [N][K] bf16 planes
__global__ void convw_kernel(const float* __restrict__ W, unsigned short* __restrict__ Wh,
                             unsigned short* __restrict__ Wl, int K, int N) {
    int idx = blockIdx.x * 256 + threadIdx.x;
    if (idx < N * K) {
        int n = idx / K, k = idx % K;
        unsigned short h, l;
        split_bf16(W[(size_t)k * N + n], h, l);
        Wh[idx] = h; Wl[idx] = l;
    }
}

// ---------------- aggregation kernels ----------------

// 256-dim aggregation, FEATURE-SPLIT: each launch covers 128 dims (d0 = 0 or 128)
// so the gathered working set halves (51 -> 25.6 MB) and XCD-L2 hit rate rises.
// One wave per node, float2 per lane, 4-deep unroll.
__global__ __launch_bounds__(256) void agg256_half_kernel(
        const float* __restrict__ x, const float* __restrict__ dinv,
        const int* __restrict__ ptr, const int2* __restrict__ edges,
        unsigned short* __restrict__ out_h, unsigned short* __restrict__ out_l, int d0) {
    int wv = threadIdx.x >> 6, lane = threadIdx.x & 63;
    int node = blockIdx.x * 4 + wv;
    if (node >= N_NODES) return;
    const float* xb = x + d0 + lane * 2;
    float di = dinv[node];
    float s = di * di;
    float2 v = *(const float2*)(xb + (size_t)node * IN_DIM);
    float ax = v.x * s, ay = v.y * s;
    int j = ptr[node], e1 = ptr[node + 1];
    for (; j + 3 < e1; j += 4) {
        int2 e0 = edges[j], e1_ = edges[j + 1], e2 = edges[j + 2], e3 = edges[j + 3];
        float2 u0 = *(const float2*)(xb + (size_t)e0.x * IN_DIM);
        float2 u1 = *(const float2*)(xb + (size_t)e1_.x * IN_DIM);
        float2 u2 = *(const float2*)(xb + (size_t)e2.x * IN_DIM);
        float2 u3 = *(const float2*)(xb + (size_t)e3.x * IN_DIM);
        float c0 = __int_as_float(e0.y), c1 = __int_as_float(e1_.y);
        float c2 = __int_as_float(e2.y), c3 = __int_as_float(e3.y);
        ax += c0 * u0.x + c1 * u1.x + c2 * u2.x + c3 * u3.x;
        ay += c0 * u0.y + c1 * u1.y + c2 * u2.y + c3 * u3.y;
    }
    for (; j < e1; ++j) {
        int2 e0 = edges[j];
        float c0 = __int_as_float(e0.y);
        float2 u0 = *(const float2*)(xb + (size_t)e0.x * IN_DIM);
        ax += c0 * u0.x; ay += c0 * u0.y;
    }
    unsigned short h0, l0, h1, l1;
    split_bf16(ax, h0, l0);
    split_bf16(ay, h1, l1);
    size_t o = (size_t)node * IN_DIM + d0;
    ((unsigned*)(out_h + o))[lane] = (unsigned)h0 | ((unsigned)h1 << 16);
    ((unsigned*)(out_l + o))[lane] = (unsigned)l0 | ((unsigned)l1 << 16);
}

// 128-dim aggregation fused with +bias and PReLU: one wave per node, float2 per lane.
// (left unsplit as the control for the L2-hypothesis A/B)
__global__ __launch_bounds__(256) void agg128_epi_kernel(
        const float* __restrict__ xw, const float* __restrict__ dinv,
        const int* __restrict__ ptr, const int2* __restrict__ edges,
        const float* __restrict__ b2, const float* __restrict__ alphap,
        float* __restrict__ out) {
    int wv = threadIdx.x >> 6, lane = threadIdx.x & 63;
    int node = blockIdx.x * 4 + wv;
    if (node >= N_NODES) return;
    const float2* x2 = (const float2*)xw;
    float di = dinv[node];
    float s = di * di;
    float2 v = x2[node * 64 + lane];
    float ax = v.x * s, ay = v.y * s;
    int j = ptr[node], e1 = ptr[node + 1];
    for (; j + 3 < e1; j += 4) {
        int2 e0 = edges[j], e1_ = edges[j + 1], e2 = edges[j + 2], e3 = edges[j + 3];
        float2 u0 = x2[e0.x * 64 + lane];
        float2 u1 = x2[e1_.x * 64 + lane];
        float2 u2 = x2[e2.x * 64 + lane];
        float2 u3 = x2[e3.x * 64 + lane];
        float c0 = __int_as_float(e0.y), c1 = __int_as_float(e1_.y);
        float c2 = __int_as_float(e2.y), c3 = __int_as_float(e3.y);
        ax += c0 * u0.x + c1 * u1.x + c2 * u2.x + c3 * u3.x;
        ay += c0 * u0.y + c1 * u1.y + c2 * u2.y + c3 * u3.y;
    }
    for (; j < e1; ++j) {
        int2 e0 = edges[j];
        float c0 = __int_as_float(e0.y);
        float2 u0 = x2[e0.x * 64 + lane];
        ax += c0 * u0.x; ay += c0 * u0.y;
    }
    float alpha = alphap[0];
    float2 b = ((const float2*)b2)[lane];
    ax += b.x; ay += b.y;
    ax = (ax >= 0.f) ? ax : alpha * ax;
    ay = (ay >= 0.f) ? ay : alpha * ay;
    ((float2*)out)[node * 64 + lane] = make_float2(ax, ay);
}

// ---------------- bf16x3 split MFMA GEMM ----------------
// C[M,N] = A[M,K] @ B[N,K]^T, A/B as bf16 hi/lo planes. 128x128 tile, 4 waves,
// BK=64, SINGLE 64KB buffer. Pipeline per k-step: barrier(DMA done) -> ds_read
// ALL 32 frags to regs -> barrier(reads done) -> issue next-tile DMA -> 96 MFMAs
// (DMA lands under MFMA). Grid is 1-D with bijective XCD-chunk swizzle (m204) so
// same-A-panel blocks (consecutive tx) colocate on one XCD's L2.

__device__ __forceinline__ int swz(int row, int k /*ushort idx, mult of 8*/) {
    return ((row << 7) + (k << 1)) ^ ((row & 7) << 4);
}

__device__ __forceinline__ void gload16(const void* g, void* l) {
    __builtin_amdgcn_global_load_lds(
        (const __attribute__((address_space(1))) unsigned int*)g,
        (__attribute__((address_space(3))) unsigned int*)l, 16, 0, 0);
}

// stage one [128][64] bf16 plane; wave w covers rows [w*32, w*32+32)
__device__ __forceinline__ void stage_plane_async(
        const unsigned short* __restrict__ gbase,  // plane, row-major [*][K]
        unsigned short* lds, int K, int grow0, int k0, int wave, int lane) {
    int r8 = lane >> 3;                 // row within 8-row group == row&7 of lds row
    int kk = k0 + (((lane & 7) ^ r8) << 3);   // inverse-swizzled k (units of 8 bf16 = 16B)
#pragma unroll
    for (int t = 0; t < 4; ++t) {
        int rowblk = wave * 32 + t * 8;
        const unsigned short* g = gbase + (size_t)(grow0 + rowblk + r8) * K + kk;
        gload16(g, lds + (size_t)rowblk * 64);  // wave-uniform base; HW adds lane*16B
    }
}

template <int MODE>
__global__ __launch_bounds__(256, 2) void gemm_mfma_kernel(
        const unsigned short* __restrict__ A_hi, const unsigned short* __restrict__ A_lo,
        const unsigned short* __restrict__ B_hi, const unsigned short* __restrict__ B_lo,
        const float* __restrict__ bias, const float* __restrict__ alphap,
        unsigned short* __restrict__ Oh, unsigned short* __restrict__ Ol,
        float* __restrict__ Of, int M, int N, int K, int tilesX) {
    __shared__ unsigned short smem[4][8192];   // Ah, Al, Bh, Bl planes: [128][64] each
    unsigned short* Ah = smem[0];
    unsigned short* Al = smem[1];
    unsigned short* Bh = smem[2];
    unsigned short* Bl = smem[3];

    const int tid  = threadIdx.x;
    const int lane = tid & 63, wave = tid >> 6;
    const int wm = wave >> 1, wn = wave & 1;
    const int lr = lane & 15, lk = (lane >> 4) << 3;

    // bijective XCD-chunk swizzle (m204): consecutive swizzled ids stay on one XCD
    const int nwg = gridDim.x;
    const int q_ = nwg >> 3, r_ = nwg & 7;
    const int xcd = blockIdx.x & 7, idx = blockIdx.x >> 3;
    const int wg = ((xcd < r_) ? xcd * (q_ + 1) : r_ * (q_ + 1) + (xcd - r_) * q_) + idx;
    const int m0 = (wg / tilesX) * 128, n0 = (wg % tilesX) * 128;

    float4v acc[4][4] = {};

    stage_plane_async(A_hi, Ah, K, m0, 0, wave, lane);
    stage_plane_async(A_lo, Al, K, m0, 0, wave, lane);
    stage_plane_async(B_hi, Bh, K, n0, 0, wave, lane);
    stage_plane_async(B_lo, Bl, K, n0, 0, wave, lane);

    for (int k0 = 0; k0 < K; k0 += 64) {
        __syncthreads();   // drain DMA for this tile
        short8v ah[2][4], al[2][4], bh[2][4], bl[2][4];
#pragma unroll
        for (int q = 0; q < 2; ++q)
#pragma unroll
            for (int i = 0; i < 4; ++i) {
                ah[q][i] = *(const short8v*)((const char*)Ah + swz(wm * 64 + i * 16 + lr, q * 32 + lk));
                al[q][i] = *(const short8v*)((const char*)Al + swz(wm * 64 + i * 16 + lr, q * 32 + lk));
                bh[q][i] = *(const short8v*)((const char*)Bh + swz(wn * 64 + i * 16 + lr, q * 32 + lk));
                bl[q][i] = *(const short8v*)((const char*)Bl + swz(wn * 64 + i * 16 + lr, q * 32 + lk));
            }
        __syncthreads();   // all waves done reading -> safe to overwrite buffer
        if (k0 + 64 < K) {
            stage_plane_async(A_hi, Ah, K, m0, k0 + 64, wave, lane);
            stage_plane_async(A_lo, Al, K, m0, k0 + 64, wave, lane);
            stage_plane_async(B_hi, Bh, K, n0, k0 + 64, wave, lane);
            stage_plane_async(B_lo, Bl, K, n0, k0 + 64, wave, lane);
        }
#pragma unroll
        for (int q = 0; q < 2; ++q)
#pragma unroll
            for (int mi = 0; mi < 4; ++mi)
#pragma unroll
                for (int ni = 0; ni < 4; ++ni) {
                    acc[mi][ni] = __builtin_amdgcn_mfma_f32_16x16x32_bf16(ah[q][mi], bh[q][ni], acc[mi][ni], 0, 0, 0);
                    acc[mi][ni] = __builtin_amdgcn_mfma_f32_16x16x32_bf16(ah[q][mi], bl[q][ni], acc[mi][ni], 0, 0, 0);
                    acc[mi][ni] = __builtin_amdgcn_mfma_f32_16x16x32_bf16(al[q][mi], bh[q][ni], acc[mi][ni], 0, 0, 0);
                }
    }

    const float alpha = (MODE == 1) ? alphap[0] : 0.f;
#pragma unroll
    for (int mi = 0; mi < 4; ++mi) {
        int grow_base = m0 + wm * 64 + mi * 16 + (lane >> 4) * 4;
#pragma unroll
        for (int ni = 0; ni < 4; ++ni) {
            int gcol = n0 + wn * 64 + ni * 16 + lr;
#pragma unroll
            for (int r = 0; r < 4; ++r) {
                int grow = grow_base + r;
                if (grow < M) {
                    float v = acc[mi][ni][r];
                    if (MODE == 1) {
                        v += bias[gcol];
                        v = (v >= 0.f) ? v : alpha * v;
                        unsigned short h, l;
                        split_bf16(v, h, l);
                        Oh[(size_t)grow * N + gcol] = h;
                        Ol[(size_t)grow * N + gcol] = l;
                    } else {
                        Of[(size_t)grow * N + gcol] = v;
                    }
                }
            }
        }
    }
}

// ---------------- launch ----------------

extern "C" void kernel_launch(void* const* d_in, const int* in_sizes, int n_in,
                              void* d_out, int out_size, void* d_ws, size_t ws_size,
                              hipStream_t stream) {
    const float* x     = (const float*)d_in[0];
    const float* eattr = (const float*)d_in[1];
    const float* W1    = (const float*)d_in[2];
    const float* b1    = (const float*)d_in[3];
    const float* W2    = (const float*)d_in[4];
    const float* b2    = (const float*)d_in[5];
    const float* alpha = (const float*)d_in[6];
    const int*   eidx  = (const int*)d_in[7];
    const int* row = eidx;
    const int* col = eidx + N_EDGES;
    float* out = (float*)d_out;

    // workspace layout (4B units); xw2 aliases aggx_h region (dead after gemm1)
    float* ws_f = (float*)d_ws;
    size_t off = 0;
    float* deg   = ws_f + off; off += N_NODES;
    float* dinv  = ws_f + off; off += N_NODES;
    int2*  edges = (int2*)(ws_f + off); off += (size_t)2 * N_EDGES;   // packed (src, coef)
    unsigned short* aggx_h = (unsigned short*)(ws_f + off); off += (size_t)N_NODES * IN_DIM / 2; // bf16 plane
    unsigned short* aggx_l = (unsigned short*)(ws_f + off); off += (size_t)N_NODES * IN_DIM / 2;
    float* xw2 = (float*)aggx_h;  // 6.4M floats, fits in aggx_h plane region (dead after gemm1)
    unsigned short* feat1_h = (unsigned short*)(ws_f + off); off += (size_t)N_NODES * H1 / 2;
    unsigned short* feat1_l = (unsigned short*)(ws_f + off); off += (size_t)N_NODES * H1 / 2;
    unsigned short* W1t_h = (unsigned short*)(ws_f + off); off += (size_t)IN_DIM * H1 / 2;
    unsigned short* W1t_l = (unsigned short*)(ws_f + off); off += (size_t)IN_DIM * H1 / 2;
    unsigned short* W2t_h = (unsigned short*)(ws_f + off); off += (size_t)H1 * H2 / 2;
    unsigned short* W2t_l = (unsigned short*)(ws_f + off); off += (size_t)H1 * H2 / 2;
    int* cnt  = (int*)(ws_f + off); off += N_NODES;
    int* ptr  = (int*)(ws_f + off); off += N_NODES + 1;
    int* fill = (int*)(ws_f + off); off += N_NODES;
    int* part = (int*)(ws_f + off); off += N_NODES;
    int* bsum = (int*)(ws_f + off); off += 256;
    int* boff = (int*)(ws_f + off); off += 256;

    const int nodeBlocks = (N_NODES + 255) / 256;   // 196
    const int edgeBlocks = (N_EDGES + 255) / 256;   // 3125

    // 0) weight conversion (tiny)
    convw_kernel<<<(IN_DIM * H1 + 255) / 256, 256, 0, stream>>>(W1, W1t_h, W1t_l, IN_DIM, H1);
    convw_kernel<<<(H1 * H2 + 255) / 256, 256, 0, stream>>>(W2, W2t_h, W2t_l, H1, H2);

    // 1) CSR build + normalization coefficients
    init_kernel<<<nodeBlocks, 256, 0, stream>>>(deg, cnt, N_NODES);
    edge_deg_kernel<<<edgeBlocks, 256, 0, stream>>>(col, eattr, deg, cnt, N_EDGES);
    dinv_kernel<<<nodeBlocks, 256, 0, stream>>>(deg, dinv, N_NODES);
    scan_block_kernel<<<nodeBlocks, 256, 0, stream>>>(cnt, part, bsum, N_NODES);
    scan_tops_kernel<<<1, 256, 0, stream>>>(bsum, boff, nodeBlocks);
    scan_add_kernel<<<nodeBlocks, 256, 0, stream>>>(part, boff, ptr, fill, N_NODES);
    scatter_kernel<<<edgeBlocks, 256, 0, stream>>>(row, col, eattr, dinv, fill, edges, N_EDGES);

    // 2) layer 1: aggregate X in two feature-half passes -> bf16 hi/lo, then MFMA GEMM
    agg256_half_kernel<<<(N_NODES + 3) / 4, 256, 0, stream>>>(x, dinv, ptr, edges, aggx_h, aggx_l, 0);
    agg256_half_kernel<<<(N_NODES + 3) / 4, 256, 0, stream>>>(x, dinv, ptr, edges, aggx_h, aggx_l, 128);
    {
        int tilesX = H1 / 128, tilesY = (N_NODES + 127) / 128;   // 4 x 391
        gemm_mfma_kernel<1><<<tilesX * tilesY, 256, 0, stream>>>(
            aggx_h, aggx_l, W1t_h, W1t_l, b1, alpha, feat1_h, feat1_l, nullptr,
            N_NODES, H1, IN_DIM, tilesX);
    }

    // 3) layer 2: MFMA GEMM 512->128 (fp32 out), then aggregate (128-dim) + bias + PReLU
    {
        int tilesX = H2 / 128, tilesY = (N_NODES + 127) / 128;   // 1 x 391
        gemm_mfma_kernel<0><<<tilesX * tilesY, 256, 0, stream>>>(
            feat1_h, feat1_l, W2t_h, W2t_l, nullptr, nullptr, nullptr, nullptr, xw2,
            N_NODES, H2, H1, tilesX);
    }
    agg128_epi_kernel<<<(N_NODES + 3) / 4, 256, 0, stream>>>(xw2, dinv, ptr, edges, b2, alpha, out);
}

// Round 9
// 488.288 us; speedup vs baseline: 1.4046x; 1.0631x over previous
//
#include <hip/hip_runtime.h>

#define N_NODES 50000
#define N_EDGES 800000
#define IN_DIM  256
#define H1      512
#define H2      128

typedef __attribute__((ext_vector_type(8))) short  short8v;
typedef __attribute__((ext_vector_type(4))) float  float4v;
typedef __attribute__((ext_vector_type(4))) unsigned uint4v;

// split fp32 -> bf16 hi + bf16 lo (RNE both); v ~= hi + lo with ~16 mantissa bits
__device__ __forceinline__ void split_bf16(float v, unsigned short& h, unsigned short& l) {
    unsigned u = __builtin_bit_cast(unsigned, v);
    unsigned hr = (u + 0x7FFFu + ((u >> 16) & 1u)) >> 16;       // RNE to bf16
    float hf = __builtin_bit_cast(float, hr << 16);
    float lf = v - hf;
    unsigned ul = __builtin_bit_cast(unsigned, lf);
    unsigned lr = (ul + 0x7FFFu + ((ul >> 16) & 1u)) >> 16;
    h = (unsigned short)hr; l = (unsigned short)lr;
}

// ---------------- CSR build kernels ----------------

__global__ void init_kernel(float* deg, int* cnt, int n) {
    int i = blockIdx.x * blockDim.x + threadIdx.x;
    if (i < n) { deg[i] = 1.0f; cnt[i] = 0; }   // deg starts at 1.0 (self-loop weight)
}

__global__ void edge_deg_kernel(const int* __restrict__ col, const float* __restrict__ ew,
                                float* deg, int* cnt, int ne) {
    int e = blockIdx.x * blockDim.x + threadIdx.x;
    if (e < ne) {
        int c = col[e];
        atomicAdd(&deg[c], ew[e]);
        atomicAdd(&cnt[c], 1);
    }
}

__global__ void dinv_kernel(const float* __restrict__ deg, float* dinv, int n) {
    int i = blockIdx.x * blockDim.x + threadIdx.x;
    if (i < n) dinv[i] = rsqrtf(deg[i]);  // deg >= 1 always (self-loop)
}

// hierarchical exclusive scan: per-block scan -> top scan -> add offsets
__global__ void scan_block_kernel(const int* __restrict__ cnt, int* __restrict__ part,
                                  int* __restrict__ bsum, int n) {
    __shared__ int s[256];
    int tid = threadIdx.x;
    int i = blockIdx.x * 256 + tid;
    int v = (i < n) ? cnt[i] : 0;
    s[tid] = v; __syncthreads();
#pragma unroll
    for (int d = 1; d < 256; d <<= 1) {
        int t = (tid >= d) ? s[tid - d] : 0; __syncthreads();
        s[tid] += t; __syncthreads();
    }
    if (i < n) part[i] = s[tid] - v;           // exclusive within block
    if (tid == 255) bsum[blockIdx.x] = s[255]; // block total
}

__global__ void scan_tops_kernel(const int* __restrict__ bsum, int* __restrict__ boff, int nb) {
    __shared__ int s[256];
    int tid = threadIdx.x;
    int v = (tid < nb) ? bsum[tid] : 0;
    s[tid] = v; __syncthreads();
#pragma unroll
    for (int d = 1; d < 256; d <<= 1) {
        int t = (tid >= d) ? s[tid - d] : 0; __syncthreads();
        s[tid] += t; __syncthreads();
    }
    if (tid < nb) boff[tid] = s[tid] - v;      // exclusive across blocks
}

__global__ void scan_add_kernel(const int* __restrict__ part, const int* __restrict__ boff,
                                int* __restrict__ ptr, int* __restrict__ fill, int n) {
    int i = blockIdx.x * 256 + threadIdx.x;
    if (i < n) {
        int p = part[i] + boff[blockIdx.x];
        ptr[i] = p; fill[i] = p;
    }
    if (i == 0) ptr[n] = N_EDGES;              // total edges known at compile time
}

// packed edge record: .x = src node, .y = coef bits (one 8B store/load per edge)
__global__ void scatter_kernel(const int* __restrict__ row, const int* __restrict__ col,
                               const float* __restrict__ ew, const float* __restrict__ dinv,
                               int* fill, int2* __restrict__ edges, int ne) {
    int e = blockIdx.x * blockDim.x + threadIdx.x;
    if (e < ne) {
        int r = row[e], c = col[e];
        int pos = atomicAdd(&fill[c], 1);
        float w = dinv[r] * ew[e] * dinv[c];
        edges[pos] = make_int2(r, __float_as_int(w));
    }
}

// weight convert: W [K][N] row-major fp32 -> Wt_hi/Wt_lo [N][K] bf16 planes
__global__ void convw_kernel(const float* __restrict__ W, unsigned short* __restrict__ Wh,
                             unsigned short* __restrict__ Wl, int K, int N) {
    int idx = blockIdx.x * 256 + threadIdx.x;
    if (idx < N * K) {
        int n = idx / K, k = idx % K;
        unsigned short h, l;
        split_bf16(W[(size_t)k * N + n], h, l);
        Wh[idx] = h; Wl[idx] = l;
    }
}

// ---------------- aggregation kernels ----------------

// 256-dim aggregation, FEATURE-SPLIT: each launch covers 128 dims (d0 = 0 or 128)
// so the gathered working set halves (51 -> 25.6 MB) and XCD-L2 hit rate rises.
__global__ __launch_bounds__(256) void agg256_half_kernel(
        const float* __restrict__ x, const float* __restrict__ dinv,
        const int* __restrict__ ptr, const int2* __restrict__ edges,
        unsigned short* __restrict__ out_h, unsigned short* __restrict__ out_l, int d0) {
    int wv = threadIdx.x >> 6, lane = threadIdx.x & 63;
    int node = blockIdx.x * 4 + wv;
    if (node >= N_NODES) return;
    const float* xb = x + d0 + lane * 2;
    float di = dinv[node];
    float s = di * di;
    float2 v = *(const float2*)(xb + (size_t)node * IN_DIM);
    float ax = v.x * s, ay = v.y * s;
    int j = ptr[node], e1 = ptr[node + 1];
    for (; j + 3 < e1; j += 4) {
        int2 e0 = edges[j], e1_ = edges[j + 1], e2 = edges[j + 2], e3 = edges[j + 3];
        float2 u0 = *(const float2*)(xb + (size_t)e0.x * IN_DIM);
        float2 u1 = *(const float2*)(xb + (size_t)e1_.x * IN_DIM);
        float2 u2 = *(const float2*)(xb + (size_t)e2.x * IN_DIM);
        float2 u3 = *(const float2*)(xb + (size_t)e3.x * IN_DIM);
        float c0 = __int_as_float(e0.y), c1 = __int_as_float(e1_.y);
        float c2 = __int_as_float(e2.y), c3 = __int_as_float(e3.y);
        ax += c0 * u0.x + c1 * u1.x + c2 * u2.x + c3 * u3.x;
        ay += c0 * u0.y + c1 * u1.y + c2 * u2.y + c3 * u3.y;
    }
    for (; j < e1; ++j) {
        int2 e0 = edges[j];
        float c0 = __int_as_float(e0.y);
        float2 u0 = *(const float2*)(xb + (size_t)e0.x * IN_DIM);
        ax += c0 * u0.x; ay += c0 * u0.y;
    }
    unsigned short h0, l0, h1, l1;
    split_bf16(ax, h0, l0);
    split_bf16(ay, h1, l1);
    size_t o = (size_t)node * IN_DIM + d0;
    ((unsigned*)(out_h + o))[lane] = (unsigned)h0 | ((unsigned)h1 << 16);
    ((unsigned*)(out_l + o))[lane] = (unsigned)l0 | ((unsigned)l1 << 16);
}

// 128-dim aggregation fused with +bias and PReLU: one wave per node, float2 per lane.
__global__ __launch_bounds__(256) void agg128_epi_kernel(
        const float* __restrict__ xw, const float* __restrict__ dinv,
        const int* __restrict__ ptr, const int2* __restrict__ edges,
        const float* __restrict__ b2, const float* __restrict__ alphap,
        float* __restrict__ out) {
    int wv = threadIdx.x >> 6, lane = threadIdx.x & 63;
    int node = blockIdx.x * 4 + wv;
    if (node >= N_NODES) return;
    const float2* x2 = (const float2*)xw;
    float di = dinv[node];
    float s = di * di;
    float2 v = x2[node * 64 + lane];
    float ax = v.x * s, ay = v.y * s;
    int j = ptr[node], e1 = ptr[node + 1];
    for (; j + 3 < e1; j += 4) {
        int2 e0 = edges[j], e1_ = edges[j + 1], e2 = edges[j + 2], e3 = edges[j + 3];
        float2 u0 = x2[e0.x * 64 + lane];
        float2 u1 = x2[e1_.x * 64 + lane];
        float2 u2 = x2[e2.x * 64 + lane];
        float2 u3 = x2[e3.x * 64 + lane];
        float c0 = __int_as_float(e0.y), c1 = __int_as_float(e1_.y);
        float c2 = __int_as_float(e2.y), c3 = __int_as_float(e3.y);
        ax += c0 * u0.x + c1 * u1.x + c2 * u2.x + c3 * u3.x;
        ay += c0 * u0.y + c1 * u1.y + c2 * u2.y + c3 * u3.y;
    }
    for (; j < e1; ++j) {
        int2 e0 = edges[j];
        float c0 = __int_as_float(e0.y);
        float2 u0 = x2[e0.x * 64 + lane];
        ax += c0 * u0.x; ay += c0 * u0.y;
    }
    float alpha = alphap[0];
    float2 b = ((const float2*)b2)[lane];
    ax += b.x; ay += b.y;
    ax = (ax >= 0.f) ? ax : alpha * ax;
    ay = (ay >= 0.f) ? ay : alpha * ay;
    ((float2*)out)[node * 64 + lane] = make_float2(ax, ay);
}

// ---------------- bf16x3 split MFMA GEMM ----------------
// C[M,N] = A[M,K] @ B[N,K]^T, A/B as bf16 hi/lo planes. 128x128 tile, 4 waves,
// BK=64, single 64KB buffer. K-loop: barrier(DMA) -> ds_read all frags -> barrier
// -> issue next DMA -> 96 MFMAs. EPILOGUE: reuse the 64KB LDS to transpose the
// C tile so global stores are 16B-coalesced (was 128 scalar 2B stores/thread).
// Grid 1-D with bijective XCD-chunk swizzle (m204).

__device__ __forceinline__ int swz(int row, int k /*ushort idx, mult of 8*/) {
    return ((row << 7) + (k << 1)) ^ ((row & 7) << 4);
}

__device__ __forceinline__ void gload16(const void* g, void* l) {
    __builtin_amdgcn_global_load_lds(
        (const __attribute__((address_space(1))) unsigned int*)g,
        (__attribute__((address_space(3))) unsigned int*)l, 16, 0, 0);
}

// stage one [128][64] bf16 plane; wave w covers rows [w*32, w*32+32)
__device__ __forceinline__ void stage_plane_async(
        const unsigned short* __restrict__ gbase,  // plane, row-major [*][K]
        unsigned short* lds, int K, int grow0, int k0, int wave, int lane) {
    int r8 = lane >> 3;                 // row within 8-row group == row&7 of lds row
    int kk = k0 + (((lane & 7) ^ r8) << 3);   // inverse-swizzled k (units of 8 bf16 = 16B)
#pragma unroll
    for (int t = 0; t < 4; ++t) {
        int rowblk = wave * 32 + t * 8;
        const unsigned short* g = gbase + (size_t)(grow0 + rowblk + r8) * K + kk;
        gload16(g, lds + (size_t)rowblk * 64);  // wave-uniform base; HW adds lane*16B
    }
}

template <int MODE>
__global__ __launch_bounds__(256, 2) void gemm_mfma_kernel(
        const unsigned short* __restrict__ A_hi, const unsigned short* __restrict__ A_lo,
        const unsigned short* __restrict__ B_hi, const unsigned short* __restrict__ B_lo,
        const float* __restrict__ bias, const float* __restrict__ alphap,
        unsigned short* __restrict__ Oh, unsigned short* __restrict__ Ol,
        float* __restrict__ Of, int M, int N, int K, int tilesX) {
    __shared__ unsigned short smem[4][8192];   // Ah, Al, Bh, Bl planes: [128][64] each
    unsigned short* Ah = smem[0];
    unsigned short* Al = smem[1];
    unsigned short* Bh = smem[2];
    unsigned short* Bl = smem[3];

    const int tid  = threadIdx.x;
    const int lane = tid & 63, wave = tid >> 6;
    const int wm = wave >> 1, wn = wave & 1;
    const int lr = lane & 15, lk = (lane >> 4) << 3;

    // bijective XCD-chunk swizzle (m204): consecutive swizzled ids stay on one XCD
    const int nwg = gridDim.x;
    const int q_ = nwg >> 3, r_ = nwg & 7;
    const int xcd = blockIdx.x & 7, idx = blockIdx.x >> 3;
    const int wg = ((xcd < r_) ? xcd * (q_ + 1) : r_ * (q_ + 1) + (xcd - r_) * q_) + idx;
    const int m0 = (wg / tilesX) * 128, n0 = (wg % tilesX) * 128;

    float4v acc[4][4] = {};

    stage_plane_async(A_hi, Ah, K, m0, 0, wave, lane);
    stage_plane_async(A_lo, Al, K, m0, 0, wave, lane);
    stage_plane_async(B_hi, Bh, K, n0, 0, wave, lane);
    stage_plane_async(B_lo, Bl, K, n0, 0, wave, lane);

    for (int k0 = 0; k0 < K; k0 += 64) {
        __syncthreads();   // drain DMA for this tile
        short8v ah[2][4], al[2][4], bh[2][4], bl[2][4];
#pragma unroll
        for (int q = 0; q < 2; ++q)
#pragma unroll
            for (int i = 0; i < 4; ++i) {
                ah[q][i] = *(const short8v*)((const char*)Ah + swz(wm * 64 + i * 16 + lr, q * 32 + lk));
                al[q][i] = *(const short8v*)((const char*)Al + swz(wm * 64 + i * 16 + lr, q * 32 + lk));
                bh[q][i] = *(const short8v*)((const char*)Bh + swz(wn * 64 + i * 16 + lr, q * 32 + lk));
                bl[q][i] = *(const short8v*)((const char*)Bl + swz(wn * 64 + i * 16 + lr, q * 32 + lk));
            }
        __syncthreads();   // all waves done reading -> safe to overwrite buffer
        if (k0 + 64 < K) {
            stage_plane_async(A_hi, Ah, K, m0, k0 + 64, wave, lane);
            stage_plane_async(A_lo, Al, K, m0, k0 + 64, wave, lane);
            stage_plane_async(B_hi, Bh, K, n0, k0 + 64, wave, lane);
            stage_plane_async(B_lo, Bl, K, n0, k0 + 64, wave, lane);
        }
#pragma unroll
        for (int q = 0; q < 2; ++q)
#pragma unroll
            for (int mi = 0; mi < 4; ++mi)
#pragma unroll
                for (int ni = 0; ni < 4; ++ni) {
                    acc[mi][ni] = __builtin_amdgcn_mfma_f32_16x16x32_bf16(ah[q][mi], bh[q][ni], acc[mi][ni], 0, 0, 0);
                    acc[mi][ni] = __builtin_amdgcn_mfma_f32_16x16x32_bf16(ah[q][mi], bl[q][ni], acc[mi][ni], 0, 0, 0);
                    acc[mi][ni] = __builtin_amdgcn_mfma_f32_16x16x32_bf16(al[q][mi], bh[q][ni], acc[mi][ni], 0, 0, 0);
                }
    }
    // after the final barrier above, all LDS reads are done -> safe to reuse smem.

    if (MODE == 1) {
        // pack h|(l<<16) into a [128][128] u32 LDS tile, then 16B-coalesced stores.
        unsigned* tr = (unsigned*)smem;
        const float alpha = alphap[0];
#pragma unroll
        for (int mi = 0; mi < 4; ++mi)
#pragma unroll
            for (int ni = 0; ni < 4; ++ni) {
                int lcol = wn * 64 + ni * 16 + lr;
                float bv = bias[n0 + lcol];
#pragma unroll
                for (int r = 0; r < 4; ++r) {
                    int lrow = wm * 64 + mi * 16 + (lane >> 4) * 4 + r;
                    float v = acc[mi][ni][r] + bv;
                    v = (v >= 0.f) ? v : alpha * v;
                    unsigned short h, l;
                    split_bf16(v, h, l);
                    tr[lrow * 128 + lcol] = (unsigned)h | ((unsigned)l << 16);
                }
            }
        __syncthreads();
#pragma unroll
        for (int c = 0; c < 8; ++c) {
            int chunk = tid + c * 256;          // 0..2047
            int row = chunk >> 4, cb = (chunk & 15) * 8;
            int grow = m0 + row;
            if (grow < M) {
                const unsigned* p = tr + row * 128 + cb;
                uint4v u0 = *(const uint4v*)p;
                uint4v u1 = *(const uint4v*)(p + 4);
                short8v hv, lv;
#pragma unroll
                for (int i = 0; i < 4; ++i) {
                    hv[i]     = (short)(u0[i] & 0xFFFFu); lv[i]     = (short)(u0[i] >> 16);
                    hv[i + 4] = (short)(u1[i] & 0xFFFFu); lv[i + 4] = (short)(u1[i] >> 16);
                }
                *(short8v*)(Oh + (size_t)grow * N + n0 + cb) = hv;
                *(short8v*)(Ol + (size_t)grow * N + n0 + cb) = lv;
            }
        }
    } else {
        // f32 [128][128] LDS tile (64 KB), then float4-coalesced stores.
        float* tr = (float*)smem;
#pragma unroll
        for (int mi = 0; mi < 4; ++mi)
#pragma unroll
            for (int ni = 0; ni < 4; ++ni) {
                int lcol = wn * 64 + ni * 16 + lr;
#pragma unroll
                for (int r = 0; r < 4; ++r) {
                    int lrow = wm * 64 + mi * 16 + (lane >> 4) * 4 + r;
                    tr[lrow * 128 + lcol] = acc[mi][ni][r];
                }
            }
        __syncthreads();
#pragma unroll
        for (int c = 0; c < 8; ++c) {
            int chunk = tid + c * 256;
            int row = chunk >> 4, cb = (chunk & 15) * 8;
            int grow = m0 + row;
            if (grow < M) {
                const float* p = tr + row * 128 + cb;
                float4 a = *(const float4*)p;
                float4 b = *(const float4*)(p + 4);
                *(float4*)(Of + (size_t)grow * N + n0 + cb)     = a;
                *(float4*)(Of + (size_t)grow * N + n0 + cb + 4) = b;
            }
        }
    }
}

// ---------------- launch ----------------

extern "C" void kernel_launch(void* const* d_in, const int* in_sizes, int n_in,
                              void* d_out, int out_size, void* d_ws, size_t ws_size,
                              hipStream_t stream) {
    const float* x     = (const float*)d_in[0];
    const float* eattr = (const float*)d_in[1];
    const float* W1    = (const float*)d_in[2];
    const float* b1    = (const float*)d_in[3];
    const float* W2    = (const float*)d_in[4];
    const float* b2    = (const float*)d_in[5];
    const float* alpha = (const float*)d_in[6];
    const int*   eidx  = (const int*)d_in[7];
    const int* row = eidx;
    const int* col = eidx + N_EDGES;
    float* out = (float*)d_out;

    // workspace layout (4B units); xw2 aliases aggx_h region (dead after gemm1)
    float* ws_f = (float*)d_ws;
    size_t off = 0;
    float* deg   = ws_f + off; off += N_NODES;
    float* dinv  = ws_f + off; off += N_NODES;
    int2*  edges = (int2*)(ws_f + off); off += (size_t)2 * N_EDGES;   // packed (src, coef)
    unsigned short* aggx_h = (unsigned short*)(ws_f + off); off += (size_t)N_NODES * IN_DIM / 2; // bf16 plane
    unsigned short* aggx_l = (unsigned short*)(ws_f + off); off += (size_t)N_NODES * IN_DIM / 2;
    float* xw2 = (float*)aggx_h;  // 6.4M floats, fits in aggx_h plane region (dead after gemm1)
    unsigned short* feat1_h = (unsigned short*)(ws_f + off); off += (size_t)N_NODES * H1 / 2;
    unsigned short* feat1_l = (unsigned short*)(ws_f + off); off += (size_t)N_NODES * H1 / 2;
    unsigned short* W1t_h = (unsigned short*)(ws_f + off); off += (size_t)IN_DIM * H1 / 2;
    unsigned short* W1t_l = (unsigned short*)(ws_f + off); off += (size_t)IN_DIM * H1 / 2;
    unsigned short* W2t_h = (unsigned short*)(ws_f + off); off += (size_t)H1 * H2 / 2;
    unsigned short* W2t_l = (unsigned short*)(ws_f + off); off += (size_t)H1 * H2 / 2;
    int* cnt  = (int*)(ws_f + off); off += N_NODES;
    int* ptr  = (int*)(ws_f + off); off += N_NODES + 1;
    int* fill = (int*)(ws_f + off); off += N_NODES;
    int* part = (int*)(ws_f + off); off += N_NODES;
    int* bsum = (int*)(ws_f + off); off += 256;
    int* boff = (int*)(ws_f + off); off += 256;

    const int nodeBlocks = (N_NODES + 255) / 256;   // 196
    const int edgeBlocks = (N_EDGES + 255) / 256;   // 3125

    // 0) weight conversion (tiny)
    convw_kernel<<<(IN_DIM * H1 + 255) / 256, 256, 0, stream>>>(W1, W1t_h, W1t_l, IN_DIM, H1);
    convw_kernel<<<(H1 * H2 + 255) / 256, 256, 0, stream>>>(W2, W2t_h, W2t_l, H1, H2);

    // 1) CSR build + normalization coefficients
    init_kernel<<<nodeBlocks, 256, 0, stream>>>(deg, cnt, N_NODES);
    edge_deg_kernel<<<edgeBlocks, 256, 0, stream>>>(col, eattr, deg, cnt, N_EDGES);
    dinv_kernel<<<nodeBlocks, 256, 0, stream>>>(deg, dinv, N_NODES);
    scan_block_kernel<<<nodeBlocks, 256, 0, stream>>>(cnt, part, bsum, N_NODES);
    scan_tops_kernel<<<1, 256, 0, stream>>>(bsum, boff, nodeBlocks);
    scan_add_kernel<<<nodeBlocks, 256, 0, stream>>>(part, boff, ptr, fill, N_NODES);
    scatter_kernel<<<edgeBlocks, 256, 0, stream>>>(row, col, eattr, dinv, fill, edges, N_EDGES);

    // 2) layer 1: aggregate X in two feature-half passes -> bf16 hi/lo, then MFMA GEMM
    agg256_half_kernel<<<(N_NODES + 3) / 4, 256, 0, stream>>>(x, dinv, ptr, edges, aggx_h, aggx_l, 0);
    agg256_half_kernel<<<(N_NODES + 3) / 4, 256, 0, stream>>>(x, dinv, ptr, edges, aggx_h, aggx_l, 128);
    {
        int tilesX = H1 / 128, tilesY = (N_NODES + 127) / 128;   // 4 x 391
        gemm_mfma_kernel<1><<<tilesX * tilesY, 256, 0, stream>>>(
            aggx_h, aggx_l, W1t_h, W1t_l, b1, alpha, feat1_h, feat1_l, nullptr,
            N_NODES, H1, IN_DIM, tilesX);
    }

    // 3) layer 2: MFMA GEMM 512->128 (fp32 out), then aggregate (128-dim) + bias + PReLU
    {
        int tilesX = H2 / 128, tilesY = (N_NODES + 127) / 128;   // 1 x 391
        gemm_mfma_kernel<0><<<tilesX * tilesY, 256, 0, stream>>>(
            feat1_h, feat1_l, W2t_h, W2t_l, nullptr, nullptr, nullptr, nullptr, xw2,
            N_NODES, H2, H1, tilesX);
    }
    agg128_epi_kernel<<<(N_NODES + 3) / 4, 256, 0, stream>>>(xw2, dinv, ptr, edges, b2, alpha, out);
}